// Round 5
// baseline (249.943 us; speedup 1.0000x reference)
//
#include <hip/hip_runtime.h>
#include <hip/hip_bf16.h>

#define DM   1024
#define SLEN 2048
#define NH   16
#define DK   64

typedef float f32x4 __attribute__((ext_vector_type(4)));
typedef short short8 __attribute__((ext_vector_type(8)));
typedef short short4v __attribute__((ext_vector_type(4)));

__device__ __forceinline__ unsigned short f2bf(float f) {
  union { float f; unsigned int u; } x; x.f = f;
  unsigned int r = x.u + 0x7fffu + ((x.u >> 16) & 1u);   // RNE
  return (unsigned short)(r >> 16);
}

__device__ __forceinline__ void gload_lds16(const unsigned short* g, unsigned short* l) {
  __builtin_amdgcn_global_load_lds(
      (const __attribute__((address_space(1))) unsigned int*)g,
      (__attribute__((address_space(3))) unsigned int*)l, 16, 0, 0);
}

__device__ __forceinline__ f32x4 mfma32(short8 a, short8 b, f32x4 c) {
  return __builtin_amdgcn_mfma_f32_16x16x32_bf16(a, b, c, 0, 0, 0);
}

__device__ __forceinline__ f32x4 mfma16(short4v a, short4v b, f32x4 c) {
#if __has_builtin(__builtin_amdgcn_mfma_f32_16x16x16bf16_1k)
  return __builtin_amdgcn_mfma_f32_16x16x16bf16_1k(a, b, c, 0, 0, 0);
#else
  f32x4 d;
  asm volatile("v_mfma_f32_16x16x16_bf16 %0, %1, %2, %3"
               : "=v"(d) : "v"(a), "v"(b), "v"(c));
  return d;
#endif
}

// ---------------------------------------------------------------- convert
struct ConvArgs { const float* src[7]; unsigned short* dst[7]; };

__global__ __launch_bounds__(256) void conv_kernel(ConvArgs a) {
  int blk = blockIdx.x, seg, base;
  if (blk < 6144) { seg = blk >> 11; base = blk & 2047; }
  else { int t = blk - 6144; seg = 3 + (t >> 9); base = t & 511; }
  const float* s = a.src[seg];
  unsigned short* d = a.dst[seg];
  int idx = (base * 256 + (int)threadIdx.x) * 8;
  float4 v0 = *(const float4*)(s + idx);
  float4 v1 = *(const float4*)(s + idx + 4);
  unsigned short o[8];
  o[0]=f2bf(v0.x); o[1]=f2bf(v0.y); o[2]=f2bf(v0.z); o[3]=f2bf(v0.w);
  o[4]=f2bf(v1.x); o[5]=f2bf(v1.y); o[6]=f2bf(v1.z); o[7]=f2bf(v1.w);
  *(uint4*)(d + idx) = *(uint4*)o;
}

// ---------------------------------------------------------------- GEMM core
// BK=64, XOR-swizzled 16B chunks in LDS. TM=128 fixed, TN=64: 4 waves each
// 64x32; grid doubles vs TN=128 -> better small-K occupancy.
// mode 0: bf16 out [B,H,S,DK] scaled. mode 1: fp32 out [M,N]. mode 2: Vt.
template <int TN>
__device__ __forceinline__ void gemm_core(int mode,
                                          const unsigned short* __restrict__ A,
                                          const unsigned short* __restrict__ W,
                                          const float* __restrict__ bias,
                                          void* __restrict__ outp, float scale,
                                          int m0, int n0,
                                          unsigned short* As, unsigned short* Bs) {
  const int tid = threadIdx.x;
  const int lane = tid & 63;
  const int l15 = lane & 15;
  const int quad = lane >> 4;
  const int wv = tid >> 6;
  const int wm = (wv >> 1) * 64, wn = (wv & 1) * (TN / 2);
  const int NB = TN / 32;

  f32x4 acc[4][NB];
#pragma unroll
  for (int i = 0; i < 4; ++i)
#pragma unroll
    for (int j = 0; j < NB; ++j) acc[i][j] = (f32x4){0.f, 0.f, 0.f, 0.f};

  for (int k0 = 0; k0 < DM; k0 += 64) {
    __syncthreads();
#pragma unroll
    for (int i = 0; i < 4; ++i) {              // A: 128x64 = 1024 chunks
      int c = tid + i * 256;
      int row = c >> 3, sc = ((c & 7) ^ (row & 7)) << 3;
      gload_lds16(A + (size_t)(m0 + row) * DM + k0 + sc, As + c * 8);
    }
#pragma unroll
    for (int i = 0; i < NB; ++i) {             // B: TNx64 = TN*8 chunks
      int c = tid + i * 256;
      int row = c >> 3, sc = ((c & 7) ^ (row & 7)) << 3;
      gload_lds16(W + (size_t)(n0 + row) * DM + k0 + sc, Bs + c * 8);
    }
    __syncthreads();
    short8 af[4][2], bf[NB][2];
#pragma unroll
    for (int i = 0; i < 4; ++i) {
      int r = wm + i * 16 + l15;
#pragma unroll
      for (int kf = 0; kf < 2; ++kf)
        af[i][kf] = *(const short8*)(As + r * 64 + (((kf * 4 + quad) ^ (r & 7)) << 3));
    }
#pragma unroll
    for (int j = 0; j < NB; ++j) {
      int r = wn + j * 16 + l15;
#pragma unroll
      for (int kf = 0; kf < 2; ++kf)
        bf[j][kf] = *(const short8*)(Bs + r * 64 + (((kf * 4 + quad) ^ (r & 7)) << 3));
    }
#pragma unroll
    for (int kf = 0; kf < 2; ++kf)
#pragma unroll
      for (int i = 0; i < 4; ++i)
#pragma unroll
        for (int j = 0; j < NB; ++j)
          acc[i][j] = mfma32(af[i][kf], bf[j][kf], acc[i][j]);
  }

#pragma unroll
  for (int i = 0; i < 4; ++i)
#pragma unroll
    for (int j = 0; j < NB; ++j) {
      int col = n0 + wn + j * 16 + l15;
      float bv = bias[col];
      int row0 = wm + i * 16 + (quad << 2) + m0;
      if (mode == 2) {
        unsigned short pk[4];
#pragma unroll
        for (int g = 0; g < 4; ++g) pk[g] = f2bf(acc[i][j][g] + bv);
        int d = col & (DK - 1), hh = col >> 6;
        int brow = row0 >> 11, srow = row0 & (SLEN - 1);
        size_t idx = ((size_t)((brow * NH + hh) * DK + d)) * SLEN + srow;
        *(uint2*)(((unsigned short*)outp) + idx) = *(uint2*)pk;
      } else if (mode == 0) {
#pragma unroll
        for (int g = 0; g < 4; ++g) {
          int row = row0 + g;
          float v = (acc[i][j][g] + bv) * scale;
          size_t idx = ((size_t)((row >> 11) * NH + (col >> 6))) * (SLEN * DK) +
                       (size_t)(row & (SLEN - 1)) * DK + (col & (DK - 1));
          ((unsigned short*)outp)[idx] = f2bf(v);
        }
      } else {
#pragma unroll
        for (int g = 0; g < 4; ++g)
          ((float*)outp)[(size_t)(row0 + g) * DM + col] = acc[i][j][g] + bv;
      }
    }
}

struct QKVArgs {
  const unsigned short* A[3];
  const unsigned short* W[3];
  const float* bias[3];
  unsigned short* out[3];
  float scale[3];
  int mode[3];
};

__global__ __launch_bounds__(256, 4) void gemm_qkv_kernel(QKVArgs a) {
  __shared__ unsigned short As[128 * 64], Bs[64 * 64];
  int z = blockIdx.z;
  gemm_core<64>(a.mode[z], a.A[z], a.W[z], a.bias[z], a.out[z], a.scale[z],
                blockIdx.x * 128, blockIdx.y * 64, As, Bs);
}

__global__ __launch_bounds__(256, 4) void gemm_o_kernel(const unsigned short* __restrict__ A,
                                                        const unsigned short* __restrict__ W,
                                                        const float* __restrict__ bias,
                                                        float* __restrict__ out) {
  __shared__ unsigned short As[128 * 64], Bs[64 * 64];
  gemm_core<64>(1, A, W, bias, out, 1.0f, blockIdx.x * 128, blockIdx.y * 64, As, Bs);
}

// ---------------------------------------------------------------- attention
// S^T formulation (S^T = K·Q^T, x32 MFMA; P fragments feed PV = V^T·P^T, x16
// MFMA, registers only). Pipelined LDS double-buffer: prefetch for tile it+1
// is issued at the TOP of iter it (post-barrier), so the global_load_lds
// latency overlaps the tile-it compute; the single end-of-iter barrier drains
// loads that have had the whole compute phase to land. Q fragments are loaded
// once directly from global (no Q LDS). 8 waves = 2 KV-groups x 4 waves
// (q=32/wave, qt=2); groups cover even/odd KV tiles, combined via LDS overlay.
__global__ __launch_bounds__(512, 4) void attn_kernel(
    const unsigned short* __restrict__ Qw,   // [B*H][S][DK] bf16, pre-scaled
    const unsigned short* __restrict__ Kw,   // [B*H][S][DK]
    const unsigned short* __restrict__ Vtw,  // [B*H][DK][S]
    const int* __restrict__ mask,            // [B][S]
    unsigned short* __restrict__ attn_out) { // [B][S][DM] bf16
  __shared__ uint4 smem4[4160];              // 66560 B
  char* smb = (char*)smem4;
  // K bufs:   smb + grp*8192 + buf*16384          (32768 B)
  // V bufs:   smb + 32768 + grp*8192 + buf*16384  (32768 B)
  // mask:     smb + 65536 + buf*512 + grp*256     (1024 B)
  float* Oex = (float*)smb;                  // epilogue overlay (33024 B)
  float* lsX = (float*)(smb + 33024);        // epilogue overlay (512 B)

  const int tid = threadIdx.x;
  const int lane = tid & 63;
  const int l15 = lane & 15;
  const int quad = lane >> 4;
  const int wv = tid >> 6;        // 0..7
  const int grp = wv >> 2;        // KV group 0/1
  const int widx = wv & 3;        // wave within group
  const int tg = tid & 255;       // thread within group

  const int s0 = blockIdx.x * 128;
  const int bh = blockIdx.y;
  const int b = bh >> 4, h = bh & 15;
  const unsigned short* Qb = Qw + (size_t)bh * (SLEN * DK);
  const unsigned short* Kb = Kw + (size_t)bh * (SLEN * DK);
  const unsigned short* Vtb = Vtw + (size_t)bh * (SLEN * DK);

  // Q fragments straight from global (one-time, loop-invariant)
  const int qb = widx * 32;
  short8 bq[2][2];
#pragma unroll
  for (int qt = 0; qt < 2; ++qt)
#pragma unroll
    for (int kf = 0; kf < 2; ++kf)
      bq[qt][kf] = *(const short8*)(Qb + (size_t)(s0 + qb + qt * 16 + l15) * DK + kf * 32 + quad * 8);

  // K/V staging chunk constants (XOR swizzle, 2+2 chunks per thread per tile)
  const int c0 = tg, c1 = tg + 256;
  const int r0c = c0 >> 3, s0c = ((c0 & 7) ^ (r0c & 7)) << 3;
  const int r1c = c1 >> 3, s1c = ((c1 & 7) ^ (r1c & 7)) << 3;

  // stage tile 0 into buf 0
  {
    unsigned short* K0 = (unsigned short*)(smb + grp * 8192);
    unsigned short* V0 = (unsigned short*)(smb + 32768 + grp * 8192);
    int kv0 = grp * 64;
    gload_lds16(Kb + (size_t)(kv0 + r0c) * DK + s0c, K0 + c0 * 8);
    gload_lds16(Kb + (size_t)(kv0 + r1c) * DK + s1c, K0 + c1 * 8);
    gload_lds16(Vtb + (size_t)r0c * SLEN + kv0 + s0c, V0 + c0 * 8);
    gload_lds16(Vtb + (size_t)r1c * SLEN + kv0 + s1c, V0 + c1 * 8);
  }
  int mreg = 1;
  if (tg < 64) {
    ((float*)(smb + 65536 + grp * 256))[tg] = mask[b * SLEN + grp * 64 + tg] ? 0.0f : -1e30f;
    mreg = mask[b * SLEN + (2 + grp) * 64 + tg];
  }
  __syncthreads();                           // tile 0 + its mask visible

  f32x4 O[4][2];                             // O^T [dt][qt], C-layout
#pragma unroll
  for (int dt = 0; dt < 4; ++dt)
#pragma unroll
    for (int qt = 0; qt < 2; ++qt) O[dt][qt] = (f32x4){0.f, 0.f, 0.f, 0.f};
  float lsum[2] = {0.f, 0.f};

  int cb = 0;
  for (int it = 0; it < 16; ++it) {
    const int nb = cb ^ 1;
    // ---- prefetch tile it+1 into buf nb (overlaps compute below)
    if (it < 15) {
      unsigned short* Kn = (unsigned short*)(smb + grp * 8192 + nb * 16384);
      unsigned short* Vn = (unsigned short*)(smb + 32768 + grp * 8192 + nb * 16384);
      int kvn = ((it + 1) * 2 + grp) * 64;
      gload_lds16(Kb + (size_t)(kvn + r0c) * DK + s0c, Kn + c0 * 8);
      gload_lds16(Kb + (size_t)(kvn + r1c) * DK + s1c, Kn + c1 * 8);
      gload_lds16(Vtb + (size_t)r0c * SLEN + kvn + s0c, Vn + c0 * 8);
      gload_lds16(Vtb + (size_t)r1c * SLEN + kvn + s1c, Vn + c1 * 8);
      if (tg < 64) {
        ((float*)(smb + 65536 + nb * 512 + grp * 256))[tg] = mreg ? 0.0f : -1e30f;
        if (it < 14) mreg = mask[b * SLEN + ((it + 2) * 2 + grp) * 64 + tg];
      }
    }

    unsigned short* KstG = (unsigned short*)(smb + grp * 8192 + cb * 16384);
    unsigned short* VstG = (unsigned short*)(smb + 32768 + grp * 8192 + cb * 16384);
    float* maskG = (float*)(smb + 65536 + cb * 512 + grp * 256);

    // ---- S^T = K·Q^T (16 x32 MFMA)
    f32x4 st[4][2];
#pragma unroll
    for (int ct = 0; ct < 4; ++ct) {
      int r = ct * 16 + l15;
      short8 ka0 = *(const short8*)(KstG + r * 64 + ((quad ^ (r & 7)) << 3));
      short8 ka1 = *(const short8*)(KstG + r * 64 + (((4 + quad) ^ (r & 7)) << 3));
#pragma unroll
      for (int qt = 0; qt < 2; ++qt) {
        f32x4 z = (f32x4){0.f, 0.f, 0.f, 0.f};
        z = mfma32(ka0, bq[qt][0], z);
        st[ct][qt] = mfma32(ka1, bq[qt][1], z);
      }
    }
    // ---- mask + exp2 + pack P fragments (registers only)
    short4v pf[4][2];
#pragma unroll
    for (int ct = 0; ct < 4; ++ct) {
      f32x4 ma = *(const f32x4*)(maskG + ct * 16 + quad * 4);
#pragma unroll
      for (int qt = 0; qt < 2; ++qt) {
        float p0 = __builtin_exp2f(st[ct][qt][0] + ma[0]);
        float p1 = __builtin_exp2f(st[ct][qt][1] + ma[1]);
        float p2 = __builtin_exp2f(st[ct][qt][2] + ma[2]);
        float p3 = __builtin_exp2f(st[ct][qt][3] + ma[3]);
        lsum[qt] += (p0 + p1) + (p2 + p3);
        union { short4v s; __hip_bfloat162 h[2]; } u;
        u.h[0] = __float22bfloat162_rn(float2{p0, p1});
        u.h[1] = __float22bfloat162_rn(float2{p2, p3});
        pf[ct][qt] = u.s;
      }
    }
    // ---- O^T += V^T·P^T (32 x16 MFMA)
#pragma unroll
    for (int dt = 0; dt < 4; ++dt) {
      int rd = dt * 16 + l15;
      short4v vf[4];
#pragma unroll
      for (int ct = 0; ct < 4; ++ct) {
        int slot = (ct * 2 + (quad >> 1)) ^ (rd & 7);
        vf[ct] = *(const short4v*)(VstG + rd * 64 + slot * 8 + (quad & 1) * 4);
      }
#pragma unroll
      for (int qt = 0; qt < 2; ++qt)
#pragma unroll
        for (int ct = 0; ct < 4; ++ct)
          O[dt][qt] = mfma16(vf[ct], pf[ct][qt], O[dt][qt]);
    }
    __syncthreads();   // drains prefetch (landed during compute); guards buf reuse
    cb = nb;
  }

  // ---- epilogue: reduce lsum across quads, combine groups via LDS overlay
#pragma unroll
  for (int qt = 0; qt < 2; ++qt) {
    lsum[qt] += __shfl_xor(lsum[qt], 16);
    lsum[qt] += __shfl_xor(lsum[qt], 32);
  }
  if (grp == 1) {
#pragma unroll
    for (int dt = 0; dt < 4; ++dt)
#pragma unroll
      for (int qt = 0; qt < 2; ++qt) {
        int qg = qb + qt * 16 + l15;
#pragma unroll
        for (int i = 0; i < 4; ++i)
          Oex[(dt * 16 + quad * 4 + i) * 129 + qg] = O[dt][qt][i];
      }
    if (quad == 0) {
      lsX[qb + lane] = lsum[0];
      lsX[qb + 16 + lane] = lsum[1];
    }
  }
  __syncthreads();
  if (grp == 0) {
#pragma unroll
    for (int qt = 0; qt < 2; ++qt) {
      int qg = qb + qt * 16 + l15;
      float inv = 1.0f / (lsum[qt] + lsX[qg]);
      int srow = s0 + qg;
#pragma unroll
      for (int dt = 0; dt < 4; ++dt) {
        int d0 = dt * 16 + quad * 4;
        unsigned short pk[4];
#pragma unroll
        for (int i = 0; i < 4; ++i)
          pk[i] = f2bf((O[dt][qt][i] + Oex[(d0 + i) * 129 + qg]) * inv);
        *(uint2*)(attn_out + (size_t)(b * SLEN + srow) * DM + h * DK + d0) = *(uint2*)pk;
      }
    }
  }
}

// ---------------------------------------------------------------- launch
extern "C" void kernel_launch(void* const* d_in, const int* in_sizes, int n_in,
                              void* d_out, int out_size, void* d_ws, size_t ws_size,
                              hipStream_t stream) {
  (void)in_sizes; (void)n_in; (void)out_size; (void)ws_size;
  const float* query = (const float*)d_in[0];
  const float* key_  = (const float*)d_in[1];
  const float* value = (const float*)d_in[2];
  const int*   mask  = (const int*)d_in[3];
  const float* Wq = (const float*)d_in[4];
  const float* bq = (const float*)d_in[5];
  const float* Wk = (const float*)d_in[6];
  const float* bk = (const float*)d_in[7];
  const float* Wv = (const float*)d_in[8];
  const float* bv = (const float*)d_in[9];
  const float* Wo = (const float*)d_in[10];
  const float* bo = (const float*)d_in[11];
  float* out = (float*)d_out;

  const size_t WSZ = 1048576, XSZ = 4194304;
  unsigned short* base = (unsigned short*)d_ws;
  unsigned short* Wqb = base;
  unsigned short* Wkb = base + WSZ;
  unsigned short* Wvb = base + 2 * WSZ;
  unsigned short* Wob = base + 3 * WSZ;
  unsigned short* Xqb = base + 4 * WSZ;
  unsigned short* Xkb = Xqb + XSZ;
  unsigned short* Xvb = Xqb + 2 * XSZ;
  unsigned short* Qw  = Xqb + 3 * XSZ;
  unsigned short* Kw  = Qw + XSZ;
  unsigned short* Vtw = Qw + 2 * XSZ;
  unsigned short* attnb = Qw + 3 * XSZ;

  ConvArgs ca;
  ca.src[0] = query; ca.src[1] = key_; ca.src[2] = value;
  ca.src[3] = Wq; ca.src[4] = Wk; ca.src[5] = Wv; ca.src[6] = Wo;
  ca.dst[0] = Xqb; ca.dst[1] = Xkb; ca.dst[2] = Xvb;
  ca.dst[3] = Wqb; ca.dst[4] = Wkb; ca.dst[5] = Wvb; ca.dst[6] = Wob;
  conv_kernel<<<8192, 256, 0, stream>>>(ca);

  QKVArgs qa;
  qa.A[0] = Xqb; qa.A[1] = Xkb; qa.A[2] = Xvb;
  qa.W[0] = Wqb; qa.W[1] = Wkb; qa.W[2] = Wvb;
  qa.bias[0] = bq; qa.bias[1] = bk; qa.bias[2] = bv;
  qa.out[0] = Qw; qa.out[1] = Kw; qa.out[2] = Vtw;
  qa.scale[0] = 0.18033688011112042f;  // log2(e)/8 folded into Q
  qa.scale[1] = 1.0f; qa.scale[2] = 1.0f;
  qa.mode[0] = 0; qa.mode[1] = 0; qa.mode[2] = 2;
  gemm_qkv_kernel<<<dim3(32, 16, 3), 256, 0, stream>>>(qa);

  attn_kernel<<<dim3(16, 32), 512, 0, stream>>>(Qw, Kw, Vtw, mask, attnb);

  gemm_o_kernel<<<dim3(32, 16), 256, 0, stream>>>(attnb, Wob, bo, out);
}